// Round 14
// baseline (12684.227 us; speedup 1.0000x reference)
//
#include <hip/hip_runtime.h>
#include <hip/hip_fp16.h>

typedef float f32x4 __attribute__((ext_vector_type(4)));
typedef float f32x16 __attribute__((ext_vector_type(16)));
typedef _Float16 half8 __attribute__((ext_vector_type(8)));
typedef _Float16 half2t __attribute__((ext_vector_type(2)));
typedef unsigned int u32;
typedef u32 u32x4v __attribute__((ext_vector_type(4)));

#define DEVI static __device__ __forceinline__

constexpr int BATCH = 32;
constexpr int TLEN  = 2048;
constexpr int HDIM  = 512;
constexpr int G3    = 1536;   // 3*H
constexpr u32 POIS  = 0xFFFFFFFFu;   // (NaN,NaN) fp16 pair — unreachable: |h|<=1 always
constexpr int NSLOT = 16;            // h ring depth (slot = step % 16)

DEVI float fast_sigmoid(float x) { return 1.0f / (1.0f + __expf(-x)); }

DEVI float fast_tanh(float x) {
  const float ax = fabsf(x);
  const float t = __expf(-2.0f * ax);
  const float r = (1.0f - t) / (1.0f + t);
  return copysignf(r, x);
}

DEVI u32 pack2h(float a, float b) {
  return __builtin_bit_cast(u32, __builtin_amdgcn_cvt_pkrtz(a, b));
}

DEVI u32 llc_load32(const u32* p) {
  return __hip_atomic_load(p, __ATOMIC_RELAXED, __HIP_MEMORY_SCOPE_AGENT);
}
DEVI void llc_store32(u32* p, u32 v) {
  __hip_atomic_store(p, v, __ATOMIC_RELAXED, __HIP_MEMORY_SCOPE_AGENT);
}

// Coherence-point loads (bypass L1/L2, like agent-scope atomic). NO waitcnt inside:
// caller drains via counted s_waitcnt + sched_barrier(0) (guide rule #18), and MUST
// drain vmcnt(0) before leaving the poll region (dangling in-flight loads whose dest
// regs get reallocated = silent corruption — round-13 lesson).
DEVI u32x4v llc_load128_async(const u32* p) {
  u32x4v r;
  asm volatile("global_load_dwordx4 %0, %1, off sc0 sc1" : "=&v"(r) : "v"(p));
  return r;
}
DEVI u32 llc_load32_async(const u32* p) {
  u32 r;
  asm volatile("global_load_dword %0, %1, off sc0 sc1" : "=&v"(r) : "v"(p));
  return r;
}

DEVI int chk4(u32x4v v) {
  return (int)((v[0] == POIS) | (v[1] == POIS) | (v[2] == POIS) | (v[3] == POIS));
}

// ---------------- weight conversion (fp32 -> fp16) ----------------
__global__ void convert_weights(const float* __restrict__ wih, const float* __restrict__ whh,
                                _Float16* __restrict__ wih_h, _Float16* __restrict__ whh_h)
{
  const size_t n = (size_t)2 * G3 * HDIM;
  for (size_t i = (size_t)blockIdx.x * blockDim.x + threadIdx.x; i < n;
       i += (size_t)gridDim.x * blockDim.x) {
    wih_h[i] = (_Float16)wih[i];
    whh_h[i] = (_Float16)whh[i];
  }
}

// ---------------- layernorm: fp32 in -> fp16 out ----------------
__global__ __launch_bounds__(256) void ln_kernel(const float* __restrict__ x,
    const float* __restrict__ gamma, const float* __restrict__ beta,
    _Float16* __restrict__ out)
{
  const int row = blockIdx.x;
  const int tid = threadIdx.x;
  const float* xr = x + (size_t)row * HDIM;
  float a = xr[tid], b = xr[tid + 256];
  float s = a + b, ss = a * a + b * b;
#pragma unroll
  for (int m = 1; m < 64; m <<= 1) {
    s  += __shfl_xor(s, m, 64);
    ss += __shfl_xor(ss, m, 64);
  }
  __shared__ float sb[8];
  const int w = tid >> 6;
  if ((tid & 63) == 0) { sb[w] = s; sb[4 + w] = ss; }
  __syncthreads();
  s  = sb[0] + sb[1] + sb[2] + sb[3];
  ss = sb[4] + sb[5] + sb[6] + sb[7];
  const float mu   = s * (1.0f / HDIM);
  const float var  = ss * (1.0f / HDIM) - mu * mu;
  const float rstd = rsqrtf(var + 1e-5f);
  out[(size_t)row * HDIM + tid]       = (_Float16)((a - mu) * rstd * gamma[tid] + beta[tid]);
  out[(size_t)row * HDIM + tid + 256] = (_Float16)((b - mu) * rstd * gamma[tid + 256] + beta[tid + 256]);
}

// ---------------- fp16 MFMA GEMM: C[m,n] = sum_k A[m,k]*W[n,k] + bias[n] ----------------
__global__ __launch_bounds__(256) void gemm_f16(
    const _Float16* __restrict__ A, const _Float16* __restrict__ W,
    const float* __restrict__ bias, _Float16* __restrict__ C,
    int t0, int lgT)
{
  __shared__ _Float16 As[128][40];
  __shared__ _Float16 Bs[128][40];
  const int bm = blockIdx.x;
  const int bn = blockIdx.y;
  const int tid = threadIdx.x;
  const int lane = tid & 63;
  const int wv = tid >> 6;
  const int wm = wv >> 1, wn = wv & 1;
  const int l15 = lane & 15, g4 = lane >> 4;
  const int tmask = (1 << lgT) - 1;

  f32x4 zero4 = {0.f, 0.f, 0.f, 0.f};
  f32x4 acc[4][4];
#pragma unroll
  for (int i = 0; i < 4; ++i) {
#pragma unroll
    for (int j = 0; j < 4; ++j) acc[i][j] = zero4;
  }

  const int srow = tid >> 2;
  const int scol = (tid & 3) * 8;
  size_t arow[2];
#pragma unroll
  for (int r2 = 0; r2 < 2; ++r2) {
    int m = bm * 128 + r2 * 64 + srow;
    int b = m >> lgT, tt = m & tmask;
    arow[r2] = ((size_t)b * TLEN + (size_t)(t0 + tt)) * HDIM;
  }
  const size_t brow0 = (size_t)(bn * 128 + srow) * HDIM;

  for (int kt = 0; kt < HDIM; kt += 32) {
#pragma unroll
    for (int r2 = 0; r2 < 2; ++r2) {
      *(uint4*)&As[r2 * 64 + srow][scol] = *(const uint4*)&A[arow[r2] + kt + scol];
      *(uint4*)&Bs[r2 * 64 + srow][scol] = *(const uint4*)&W[brow0 + (size_t)r2 * 64 * HDIM + kt + scol];
    }
    __syncthreads();
    half8 af[4], bf[4];
#pragma unroll
    for (int i = 0; i < 4; ++i) af[i] = *(const half8*)&As[wm * 64 + i * 16 + l15][g4 * 8];
#pragma unroll
    for (int j = 0; j < 4; ++j) bf[j] = *(const half8*)&Bs[wn * 64 + j * 16 + l15][g4 * 8];
#pragma unroll
    for (int i = 0; i < 4; ++i) {
#pragma unroll
      for (int j = 0; j < 4; ++j)
        acc[i][j] = __builtin_amdgcn_mfma_f32_16x16x32_f16(af[i], bf[j], acc[i][j], 0, 0, 0);
    }
    __syncthreads();
  }
#pragma unroll
  for (int j = 0; j < 4; ++j) {
    const int col = bn * 128 + wn * 64 + j * 16 + l15;
    const float bi = bias[col];
#pragma unroll
    for (int i = 0; i < 4; ++i) {
      const int mrow = bm * 128 + wm * 64 + i * 16 + g4 * 4;
#pragma unroll
      for (int r = 0; r < 4; ++r)
        C[(size_t)(mrow + r) * G3 + col] = (_Float16)(acc[i][j][r] + bi);
    }
  }
}

// ---------------- ring init: slot 0 = zeros (h_0), slots 1..15 = POISON ----------------
__global__ void init_sync(u32* __restrict__ h1ring, u32* __restrict__ h2ring,
                          u32* __restrict__ syncw)
{
  const int i = blockIdx.x * 256 + threadIdx.x;   // 0 .. 16*8192-1
  const u32 v = (i >> 13) == 0 ? 0u : POIS;
  h1ring[i] = v;
  h2ring[i] = v;
  if (i == 0) syncw[0] = 0u;
}

// ---------------- fused 2-layer persistent GRU recurrence (poison-ring sync) --------
// ROUND-12 STRUCTURE (8.68 ms) + 2-deep PIPELINED POLL + EXIT DRAIN (r13 UB fix):
// two register banks; issue bank B before counted-waiting on bank A (vmcnt(5) L1 /
// vmcnt(8) L2) -> checks every ~tau instead of every ~RT. On accept, vmcnt(0) drain
// kills the in-flight bank BEFORE any register reuse; drain is cheap (~tau) because
// banks are issued ~tau apart.
__global__ __launch_bounds__(512, 1) void gru_fused(
    const u32* __restrict__ xp,        // [BATCH][TSEG][768] u32 (fp16 pairs), layer-1 xp
    const u32* __restrict__ whh,       // [2][G3][256] u32 (fp16 pairs)
    const u32* __restrict__ wih2,      // [G3][256] u32, layer-2 W_ih
    const float* __restrict__ bhh,     // [2*G3]
    const float* __restrict__ bih2,    // [G3]
    float* __restrict__ out,           // [BATCH][TLEN][HDIM] fp32
    u32* __restrict__ h1ring,          // [16][8192]
    u32* __restrict__ h2ring,          // [16][8192]
    u32* __restrict__ syncw,           // [32]: [0] = L2 progress
    int t0, int t1, int lgT)
{
  const int l2 = blockIdx.x >> 4;
  const int c  = blockIdx.x & 15;
  const int tid = threadIdx.x;
  const int lane = tid & 63;
  const int w = tid >> 6;
  const int l31 = lane & 31;
  const int kh = lane >> 5;

  __shared__ __align__(16) u32 st_l[32 * 260];    // own state (h1 for L1 / h2 for L2)
  __shared__ __align__(16) u32 h1_l[32 * 260];    // L2 only: h1 input
  __shared__ float sg_h[96 * 33];   // W_hh result
  __shared__ float sg_i[96 * 33];   // W_ih2 result (L2)

  // one MFMA tile per wave: waves 0-2 -> W_hh gate tiles; waves 3-5 (L2) -> W_ih2 tiles
  half8 bf[32];
  const bool mfma_w = (w < 3) || (l2 && w < 6);
  if (mfma_w) {
    const int gt = (w < 3) ? w : w - 3;
    const int grow = gt * 512 + c * 32 + l31;
    const u32* wsrc = (w < 3) ? (whh + (size_t)l2 * (G3 * 256)) : wih2;
#pragma unroll
    for (int ks = 0; ks < 32; ++ks)
      bf[ks] = *(const half8*)&wsrc[(size_t)grow * 256 + ks * 8 + kh * 4];
  }

  // epilogue mapping: thread -> group ga = tid>>4, dim pair dp = tid&15
  const int dp = tid & 15;
  const int ga = tid >> 4;
  const float* bhh_l = bhh + l2 * G3;
  float biasH[3][2], biasI[3][2];
#pragma unroll
  for (int gt = 0; gt < 3; ++gt) {
    biasH[gt][0] = bhh_l[gt * 512 + c * 32 + 2 * dp];
    biasH[gt][1] = bhh_l[gt * 512 + c * 32 + 2 * dp + 1];
    biasI[gt][0] = l2 ? bih2[gt * 512 + c * 32 + 2 * dp] : 0.0f;
    biasI[gt][1] = l2 ? bih2[gt * 512 + c * 32 + 2 * dp + 1] : 0.0f;
  }

  u32* const ringOwn = l2 ? h2ring : h1ring;
  const int my = ga * 256 + c * 16 + dp;   // this thread's u32 slot within a ring slot
  u32 hpp_reg = 0;                         // carried hprev (own prior publish)

  const int r0 = tid >> 6;                 // LDS fill row within 8-row chunk
  const int cc = (tid << 2) & 255;         // LDS fill u32 col

  for (int t = t0; t < t1; ++t) {
    // L1: prefetch xp for this step (drained by the poll's first counted wait)
    u32 xu[3];
    if (!l2) {
      const size_t row = ((size_t)(ga << lgT) + (size_t)(t - t0)) * 768;
#pragma unroll
      for (int gt = 0; gt < 3; ++gt)
        xu[gt] = xp[row + gt * 256 + c * 16 + dp];
    }

    const u32* rdA = ringOwn + (size_t)(t & 15) * 8192 + (tid << 2);
    const u32* rdB = h1ring + (size_t)((t + 1) & 15) * 8192 + (tid << 2);

    if (!l2) {
      // ---- L1 pipelined poll: banks of 5 (4x dwordx4 + syncw dword) ----
      u32x4v a0, a1, a2, a3, c0, c1, c2, c3;
      u32 pr0, pr1;
      a0 = llc_load128_async(rdA);        a1 = llc_load128_async(rdA + 2048);
      a2 = llc_load128_async(rdA + 4096); a3 = llc_load128_async(rdA + 6144);
      pr0 = llc_load32_async(&syncw[0]);
      while (true) {
        c0 = llc_load128_async(rdA);        c1 = llc_load128_async(rdA + 2048);
        c2 = llc_load128_async(rdA + 4096); c3 = llc_load128_async(rdA + 6144);
        pr1 = llc_load32_async(&syncw[0]);
        asm volatile("s_waitcnt vmcnt(5)" ::: "memory");
        __builtin_amdgcn_sched_barrier(0);
        {
          const int bad = chk4(a0) | chk4(a1) | chk4(a2) | chk4(a3)
                        | (int)((int)pr0 < t - 3);
          if (!__any(bad)) {
            *(u32x4v*)&st_l[(0  + r0) * 260 + cc] = a0;
            *(u32x4v*)&st_l[(8  + r0) * 260 + cc] = a1;
            *(u32x4v*)&st_l[(16 + r0) * 260 + cc] = a2;
            *(u32x4v*)&st_l[(24 + r0) * 260 + cc] = a3;
            break;
          }
        }
        a0 = llc_load128_async(rdA);        a1 = llc_load128_async(rdA + 2048);
        a2 = llc_load128_async(rdA + 4096); a3 = llc_load128_async(rdA + 6144);
        pr0 = llc_load32_async(&syncw[0]);
        asm volatile("s_waitcnt vmcnt(5)" ::: "memory");
        __builtin_amdgcn_sched_barrier(0);
        {
          const int bad = chk4(c0) | chk4(c1) | chk4(c2) | chk4(c3)
                        | (int)((int)pr1 < t - 3);
          if (!__any(bad)) {
            *(u32x4v*)&st_l[(0  + r0) * 260 + cc] = c0;
            *(u32x4v*)&st_l[(8  + r0) * 260 + cc] = c1;
            *(u32x4v*)&st_l[(16 + r0) * 260 + cc] = c2;
            *(u32x4v*)&st_l[(24 + r0) * 260 + cc] = c3;
            break;
          }
        }
      }
    } else {
      // ---- L2 pipelined poll: banks of 8 (own h2 slot t + h1 slot t+1) ----
      u32x4v a0, a1, a2, a3, b0, b1, b2, b3;
      u32x4v c0, c1, c2, c3, d0, d1, d2, d3;
      a0 = llc_load128_async(rdA);        a1 = llc_load128_async(rdA + 2048);
      a2 = llc_load128_async(rdA + 4096); a3 = llc_load128_async(rdA + 6144);
      b0 = llc_load128_async(rdB);        b1 = llc_load128_async(rdB + 2048);
      b2 = llc_load128_async(rdB + 4096); b3 = llc_load128_async(rdB + 6144);
      while (true) {
        c0 = llc_load128_async(rdA);        c1 = llc_load128_async(rdA + 2048);
        c2 = llc_load128_async(rdA + 4096); c3 = llc_load128_async(rdA + 6144);
        d0 = llc_load128_async(rdB);        d1 = llc_load128_async(rdB + 2048);
        d2 = llc_load128_async(rdB + 4096); d3 = llc_load128_async(rdB + 6144);
        asm volatile("s_waitcnt vmcnt(8)" ::: "memory");
        __builtin_amdgcn_sched_barrier(0);
        {
          const int bad = chk4(a0) | chk4(a1) | chk4(a2) | chk4(a3)
                        | chk4(b0) | chk4(b1) | chk4(b2) | chk4(b3);
          if (!__any(bad)) {
            *(u32x4v*)&st_l[(0  + r0) * 260 + cc] = a0;
            *(u32x4v*)&st_l[(8  + r0) * 260 + cc] = a1;
            *(u32x4v*)&st_l[(16 + r0) * 260 + cc] = a2;
            *(u32x4v*)&st_l[(24 + r0) * 260 + cc] = a3;
            *(u32x4v*)&h1_l[(0  + r0) * 260 + cc] = b0;
            *(u32x4v*)&h1_l[(8  + r0) * 260 + cc] = b1;
            *(u32x4v*)&h1_l[(16 + r0) * 260 + cc] = b2;
            *(u32x4v*)&h1_l[(24 + r0) * 260 + cc] = b3;
            break;
          }
        }
        a0 = llc_load128_async(rdA);        a1 = llc_load128_async(rdA + 2048);
        a2 = llc_load128_async(rdA + 4096); a3 = llc_load128_async(rdA + 6144);
        b0 = llc_load128_async(rdB);        b1 = llc_load128_async(rdB + 2048);
        b2 = llc_load128_async(rdB + 4096); b3 = llc_load128_async(rdB + 6144);
        asm volatile("s_waitcnt vmcnt(8)" ::: "memory");
        __builtin_amdgcn_sched_barrier(0);
        {
          const int bad = chk4(c0) | chk4(c1) | chk4(c2) | chk4(c3)
                        | chk4(d0) | chk4(d1) | chk4(d2) | chk4(d3);
          if (!__any(bad)) {
            *(u32x4v*)&st_l[(0  + r0) * 260 + cc] = c0;
            *(u32x4v*)&st_l[(8  + r0) * 260 + cc] = c1;
            *(u32x4v*)&st_l[(16 + r0) * 260 + cc] = c2;
            *(u32x4v*)&st_l[(24 + r0) * 260 + cc] = c3;
            *(u32x4v*)&h1_l[(0  + r0) * 260 + cc] = d0;
            *(u32x4v*)&h1_l[(8  + r0) * 260 + cc] = d1;
            *(u32x4v*)&h1_l[(16 + r0) * 260 + cc] = d2;
            *(u32x4v*)&h1_l[(24 + r0) * 260 + cc] = d3;
            break;
          }
        }
      }
    }
    // R13 UB FIX: drain the still-in-flight bank BEFORE any register reuse.
    // Cheap (~tau): the dangling bank was issued only ~tau after the accepted one.
    asm volatile("s_waitcnt vmcnt(0)" ::: "memory");
    __builtin_amdgcn_sched_barrier(0);
    __syncthreads();   // B1

    // re-poison own region of slot used at step t+8 early — ack overlaps MFMA.
    // Safety: slot (t+9)&15 holds version t-7 data; every reader of it is >=3 steps done.
    llc_store32(&ringOwn[(size_t)((t + 9) & 15) * 8192 + c * 512 + tid], POIS);

    // hprev from own prior publish (LDS only on first iteration)
    const u32 hpp = (t == t0) ? st_l[ga * 260 + c * 16 + dp] : hpp_reg;

    if (mfma_w) {
      // ILP-2: two independent 16-deep chains, summed at the end
      f32x16 accA, accB;
#pragma unroll
      for (int i = 0; i < 16; ++i) { accA[i] = 0.0f; accB[i] = 0.0f; }
      const u32* asrc = (w < 3) ? st_l : h1_l;
#pragma unroll
      for (int ks = 0; ks < 16; ++ks) {
        const half8 afA = *(const half8*)&asrc[l31 * 260 + ks * 8 + kh * 4];
        const half8 afB = *(const half8*)&asrc[l31 * 260 + (ks + 16) * 8 + kh * 4];
        accA = __builtin_amdgcn_mfma_f32_32x32x16_f16(afA, bf[ks], accA, 0, 0, 0);
        accB = __builtin_amdgcn_mfma_f32_32x32x16_f16(afB, bf[ks + 16], accB, 0, 0, 0);
      }
      // C/D map (verified): col=l31 -> local row, row=(r&3)+8*(r>>2)+4*kh -> group
      const int gt = (w < 3) ? w : w - 3;
      float* sg = (w < 3) ? sg_h : sg_i;
#pragma unroll
      for (int r = 0; r < 16; ++r) {
        const int grp = (r & 3) + 8 * (r >> 2) + 4 * kh;
        sg[(gt * 32 + l31) * 33 + grp] = accA[r] + accB[r];
      }
    }
    __syncthreads();   // B2

    // epilogue: one group x one dim-pair per thread
    float hn0, hn1;
    {
      const half2t hp2 = __builtin_bit_cast(half2t, hpp);
      float hn[2];
#pragma unroll
      for (int dd = 0; dd < 2; ++dd) {
        const int d = 2 * dp + dd;
        float xr, xz, xn;
        if (!l2) {
          const half2t xr2 = __builtin_bit_cast(half2t, xu[0]);
          const half2t xz2 = __builtin_bit_cast(half2t, xu[1]);
          const half2t xn2 = __builtin_bit_cast(half2t, xu[2]);
          xr = (float)(dd ? xr2.y : xr2.x);
          xz = (float)(dd ? xz2.y : xz2.x);
          xn = (float)(dd ? xn2.y : xn2.x);
        } else {
          xr = sg_i[(0 * 32 + d) * 33 + ga] + biasI[0][dd];
          xz = sg_i[(32 + d) * 33 + ga]     + biasI[1][dd];
          xn = sg_i[(64 + d) * 33 + ga]     + biasI[2][dd];
        }
        const float hprev = (float)(dd ? hp2.y : hp2.x);
        const float rr = fast_sigmoid(xr + sg_h[(0 * 32 + d) * 33 + ga] + biasH[0][dd]);
        const float zz = fast_sigmoid(xz + sg_h[(32 + d) * 33 + ga]     + biasH[1][dd]);
        const float nn = fast_tanh(xn + rr * (sg_h[(64 + d) * 33 + ga]  + biasH[2][dd]));
        hn[dd] = (1.0f - zz) * nn + zz * hprev;
      }
      hn0 = hn[0]; hn1 = hn[1];
    }
    const u32 packed = pack2h(hn0, hn1);
    hpp_reg = packed;
    // publish h_{t+1} (no drain, no flag — consumers detect via poison clearing)
    llc_store32(&ringOwn[(size_t)((t + 1) & 15) * 8192 + my], packed);
    // deferred fp32 output store (off the sync path)
    if (l2) {
      float2 v; v.x = hn0; v.y = hn1;
      *(float2*)&out[((size_t)ga * TLEN + t) * HDIM + c * 32 + 2 * dp] = v;
    }
    // L2 progress (one block publishes; intra-layer skew <= 1)
    if (l2 && c == 0 && tid == 0) llc_store32(&syncw[0], (u32)(t + 1));
  }
}

// ---------------- host launcher ----------------
extern "C" void kernel_launch(void* const* d_in, const int* in_sizes, int n_in,
                              void* d_out, int out_size, void* d_ws, size_t ws_size,
                              hipStream_t stream)
{
  const float* x     = (const float*)d_in[0];
  const float* gamma = (const float*)d_in[1];
  const float* beta  = (const float*)d_in[2];
  const float* Wih   = (const float*)d_in[3];
  const float* Whh   = (const float*)d_in[4];
  const float* bih   = (const float*)d_in[5];
  const float* bhh   = (const float*)d_in[6];
  float* out = (float*)d_out;

  // ws layout: [xp][hseq 67MB][wih_h][whh_h][h1ring][h2ring][syncw]
  const size_t wbytes  = (size_t)2 * G3 * HDIM * 2;                 // 3,145,728 each
  const size_t hseqb   = (size_t)BATCH * TLEN * HDIM * 2;           // 67,108,864
  const size_t ringb   = (size_t)NSLOT * 8192 * 4;                  // 524,288 each
  const size_t fixed   = hseqb + 2 * wbytes + 2 * ringb + 4096;
  int lgT = 11;
  while (lgT > 2 && ((size_t)BATCH * ((size_t)1 << lgT) * G3 * 2 + fixed) > ws_size) --lgT;
  const int TSEG = 1 << lgT;
  const int nseg = TLEN / TSEG;

  char* ws = (char*)d_ws;
  _Float16* xp     = (_Float16*)ws;
  char* base       = ws + (size_t)BATCH * TSEG * G3 * 2;
  _Float16* hseq   = (_Float16*)base;                               // LN output (fp16)
  _Float16* wih_h  = (_Float16*)(base + hseqb);
  _Float16* whh_h  = (_Float16*)(base + hseqb + wbytes);
  u32*      h1ring = (u32*)    (base + hseqb + 2 * wbytes);
  u32*      h2ring = h1ring + (size_t)NSLOT * 8192;
  u32*      syncw  = h2ring + (size_t)NSLOT * 8192;

  convert_weights<<<512, 256, 0, stream>>>(Wih, Whh, wih_h, whh_h);
  ln_kernel<<<BATCH * TLEN, 256, 0, stream>>>(x, gamma, beta, hseq);
  init_sync<<<512, 256, 0, stream>>>(h1ring, h2ring, syncw);

  const dim3 ggrid(BATCH * TSEG / 128, 12);
  for (int s = 0; s < nseg; ++s) {
    const int t0 = s * TSEG;
    gemm_f16<<<ggrid, 256, 0, stream>>>(hseq, wih_h, bih, xp, t0, lgT);
    gru_fused<<<32, 512, 0, stream>>>((const u32*)xp, (const u32*)whh_h,
                                      (const u32*)(wih_h + (size_t)G3 * HDIM),
                                      bhh, bih + G3, out,
                                      h1ring, h2ring, syncw, t0, t0 + TSEG, lgT);
  }
}

// Round 15
// 8667.965 us; speedup vs baseline: 1.4633x; 1.4633x over previous
//
#include <hip/hip_runtime.h>
#include <hip/hip_fp16.h>

typedef float f32x4 __attribute__((ext_vector_type(4)));
typedef float f32x16 __attribute__((ext_vector_type(16)));
typedef _Float16 half8 __attribute__((ext_vector_type(8)));
typedef _Float16 half2t __attribute__((ext_vector_type(2)));
typedef unsigned int u32;
typedef u32 u32x4v __attribute__((ext_vector_type(4)));

#define DEVI static __device__ __forceinline__

constexpr int BATCH = 32;
constexpr int TLEN  = 2048;
constexpr int HDIM  = 512;
constexpr int G3    = 1536;   // 3*H
constexpr u32 POIS  = 0xFFFFFFFFu;   // (NaN,NaN) fp16 pair — unreachable: |h|<=1 always
constexpr int NSLOT = 16;            // h ring depth (slot = step % 16)

DEVI float fast_sigmoid(float x) { return 1.0f / (1.0f + __expf(-x)); }

DEVI float fast_tanh(float x) {
  const float ax = fabsf(x);
  const float t = __expf(-2.0f * ax);
  const float r = (1.0f - t) / (1.0f + t);
  return copysignf(r, x);
}

DEVI u32 pack2h(float a, float b) {
  return __builtin_bit_cast(u32, __builtin_amdgcn_cvt_pkrtz(a, b));
}

DEVI u32 llc_load32(const u32* p) {
  return __hip_atomic_load(p, __ATOMIC_RELAXED, __HIP_MEMORY_SCOPE_AGENT);
}
DEVI void llc_store32(u32* p, u32 v) {
  __hip_atomic_store(p, v, __ATOMIC_RELAXED, __HIP_MEMORY_SCOPE_AGENT);
}

// 16B coherence-point load (bypasses L1/L2, like agent-scope atomic). NO waitcnt
// inside: caller drains vmcnt and fences with sched_barrier(0) (guide rule #18).
// NEVER leave a poll region with in-flight loads (round-13 lesson: reallocated
// dest regs + landing loads = silent corruption).
DEVI u32x4v llc_load128_async(const u32* p) {
  u32x4v r;
  asm volatile("global_load_dwordx4 %0, %1, off sc0 sc1" : "=&v"(r) : "v"(p));
  return r;
}

DEVI int chk4(u32x4v v) {
  return (int)((v[0] == POIS) | (v[1] == POIS) | (v[2] == POIS) | (v[3] == POIS));
}

// ---------------- weight conversion (fp32 -> fp16) ----------------
__global__ void convert_weights(const float* __restrict__ wih, const float* __restrict__ whh,
                                _Float16* __restrict__ wih_h, _Float16* __restrict__ whh_h)
{
  const size_t n = (size_t)2 * G3 * HDIM;
  for (size_t i = (size_t)blockIdx.x * blockDim.x + threadIdx.x; i < n;
       i += (size_t)gridDim.x * blockDim.x) {
    wih_h[i] = (_Float16)wih[i];
    whh_h[i] = (_Float16)whh[i];
  }
}

// ---------------- layernorm: fp32 in -> fp16 out ----------------
__global__ __launch_bounds__(256) void ln_kernel(const float* __restrict__ x,
    const float* __restrict__ gamma, const float* __restrict__ beta,
    _Float16* __restrict__ out)
{
  const int row = blockIdx.x;
  const int tid = threadIdx.x;
  const float* xr = x + (size_t)row * HDIM;
  float a = xr[tid], b = xr[tid + 256];
  float s = a + b, ss = a * a + b * b;
#pragma unroll
  for (int m = 1; m < 64; m <<= 1) {
    s  += __shfl_xor(s, m, 64);
    ss += __shfl_xor(ss, m, 64);
  }
  __shared__ float sb[8];
  const int w = tid >> 6;
  if ((tid & 63) == 0) { sb[w] = s; sb[4 + w] = ss; }
  __syncthreads();
  s  = sb[0] + sb[1] + sb[2] + sb[3];
  ss = sb[4] + sb[5] + sb[6] + sb[7];
  const float mu   = s * (1.0f / HDIM);
  const float var  = ss * (1.0f / HDIM) - mu * mu;
  const float rstd = rsqrtf(var + 1e-5f);
  out[(size_t)row * HDIM + tid]       = (_Float16)((a - mu) * rstd * gamma[tid] + beta[tid]);
  out[(size_t)row * HDIM + tid + 256] = (_Float16)((b - mu) * rstd * gamma[tid + 256] + beta[tid + 256]);
}

// ---------------- fp16 MFMA GEMM: C[m,n] = sum_k A[m,k]*W[n,k] + bias[n] ----------------
__global__ __launch_bounds__(256) void gemm_f16(
    const _Float16* __restrict__ A, const _Float16* __restrict__ W,
    const float* __restrict__ bias, _Float16* __restrict__ C,
    int t0, int lgT)
{
  __shared__ _Float16 As[128][40];
  __shared__ _Float16 Bs[128][40];
  const int bm = blockIdx.x;
  const int bn = blockIdx.y;
  const int tid = threadIdx.x;
  const int lane = tid & 63;
  const int wv = tid >> 6;
  const int wm = wv >> 1, wn = wv & 1;
  const int l15 = lane & 15, g4 = lane >> 4;
  const int tmask = (1 << lgT) - 1;

  f32x4 zero4 = {0.f, 0.f, 0.f, 0.f};
  f32x4 acc[4][4];
#pragma unroll
  for (int i = 0; i < 4; ++i) {
#pragma unroll
    for (int j = 0; j < 4; ++j) acc[i][j] = zero4;
  }

  const int srow = tid >> 2;
  const int scol = (tid & 3) * 8;
  size_t arow[2];
#pragma unroll
  for (int r2 = 0; r2 < 2; ++r2) {
    int m = bm * 128 + r2 * 64 + srow;
    int b = m >> lgT, tt = m & tmask;
    arow[r2] = ((size_t)b * TLEN + (size_t)(t0 + tt)) * HDIM;
  }
  const size_t brow0 = (size_t)(bn * 128 + srow) * HDIM;

  for (int kt = 0; kt < HDIM; kt += 32) {
#pragma unroll
    for (int r2 = 0; r2 < 2; ++r2) {
      *(uint4*)&As[r2 * 64 + srow][scol] = *(const uint4*)&A[arow[r2] + kt + scol];
      *(uint4*)&Bs[r2 * 64 + srow][scol] = *(const uint4*)&W[brow0 + (size_t)r2 * 64 * HDIM + kt + scol];
    }
    __syncthreads();
    half8 af[4], bf[4];
#pragma unroll
    for (int i = 0; i < 4; ++i) af[i] = *(const half8*)&As[wm * 64 + i * 16 + l15][g4 * 8];
#pragma unroll
    for (int j = 0; j < 4; ++j) bf[j] = *(const half8*)&Bs[wn * 64 + j * 16 + l15][g4 * 8];
#pragma unroll
    for (int i = 0; i < 4; ++i) {
#pragma unroll
      for (int j = 0; j < 4; ++j)
        acc[i][j] = __builtin_amdgcn_mfma_f32_16x16x32_f16(af[i], bf[j], acc[i][j], 0, 0, 0);
    }
    __syncthreads();
  }
#pragma unroll
  for (int j = 0; j < 4; ++j) {
    const int col = bn * 128 + wn * 64 + j * 16 + l15;
    const float bi = bias[col];
#pragma unroll
    for (int i = 0; i < 4; ++i) {
      const int mrow = bm * 128 + wm * 64 + i * 16 + g4 * 4;
#pragma unroll
      for (int r = 0; r < 4; ++r)
        C[(size_t)(mrow + r) * G3 + col] = (_Float16)(acc[i][j][r] + bi);
    }
  }
}

// ---------------- ring init: slot 0 = zeros (h_0), slots 1..15 = POISON ----------------
__global__ void init_sync(u32* __restrict__ h1ring, u32* __restrict__ h2ring,
                          u32* __restrict__ syncw)
{
  const int i = blockIdx.x * 256 + threadIdx.x;   // 0 .. 16*8192-1
  const u32 v = (i >> 13) == 0 ? 0u : POIS;
  h1ring[i] = v;
  h2ring[i] = v;
  if (i == 0) syncw[0] = 0u;
}

// ---------------- fused 2-layer persistent GRU recurrence (poison-ring sync) --------
// ROUND-12 PROVEN STATE (8.68 ms, step 4.13 us). Structure:
// 32 blocks: layer = bid>>4, c = bid&15 owns dims [c*32, c*32+32).
// h exchange: 16-slot rings keyed by absolute step. Consumers poll the DATA
// (per-wave dwordx4 sc0 sc1, single bank, vmcnt(0) drain + s_sleep) until no word
// == POISON — detection IS the reload. Producers: plain agent stores, no drain/flag.
// Re-poison slot (t+9)%16 early (ack overlaps MFMA). L1 gates on L2 progress >= t-3.
// ILP-2 MFMA chains; hprev carried in registers.
// Step floor analysis (r7-r14): compute ~1.2us + store-visibility ~RT + detect/reload
// ~RT + skew ~= 4.1us. Denser sampling (r13/r14) hurts via LLC contention + drain RT.
__global__ __launch_bounds__(512, 1) void gru_fused(
    const u32* __restrict__ xp,        // [BATCH][TSEG][768] u32 (fp16 pairs), layer-1 xp
    const u32* __restrict__ whh,       // [2][G3][256] u32 (fp16 pairs)
    const u32* __restrict__ wih2,      // [G3][256] u32, layer-2 W_ih
    const float* __restrict__ bhh,     // [2*G3]
    const float* __restrict__ bih2,    // [G3]
    float* __restrict__ out,           // [BATCH][TLEN][HDIM] fp32
    u32* __restrict__ h1ring,          // [16][8192]
    u32* __restrict__ h2ring,          // [16][8192]
    u32* __restrict__ syncw,           // [32]: [0] = L2 progress
    int t0, int t1, int lgT)
{
  const int l2 = blockIdx.x >> 4;
  const int c  = blockIdx.x & 15;
  const int tid = threadIdx.x;
  const int lane = tid & 63;
  const int w = tid >> 6;
  const int l31 = lane & 31;
  const int kh = lane >> 5;

  __shared__ __align__(16) u32 st_l[32 * 260];    // own state (h1 for L1 / h2 for L2)
  __shared__ __align__(16) u32 h1_l[32 * 260];    // L2 only: h1 input
  __shared__ float sg_h[96 * 33];   // W_hh result
  __shared__ float sg_i[96 * 33];   // W_ih2 result (L2)

  // one MFMA tile per wave: waves 0-2 -> W_hh gate tiles; waves 3-5 (L2) -> W_ih2 tiles
  half8 bf[32];
  const bool mfma_w = (w < 3) || (l2 && w < 6);
  if (mfma_w) {
    const int gt = (w < 3) ? w : w - 3;
    const int grow = gt * 512 + c * 32 + l31;
    const u32* wsrc = (w < 3) ? (whh + (size_t)l2 * (G3 * 256)) : wih2;
#pragma unroll
    for (int ks = 0; ks < 32; ++ks)
      bf[ks] = *(const half8*)&wsrc[(size_t)grow * 256 + ks * 8 + kh * 4];
  }

  // epilogue mapping: thread -> group ga = tid>>4, dim pair dp = tid&15
  const int dp = tid & 15;
  const int ga = tid >> 4;
  const float* bhh_l = bhh + l2 * G3;
  float biasH[3][2], biasI[3][2];
#pragma unroll
  for (int gt = 0; gt < 3; ++gt) {
    biasH[gt][0] = bhh_l[gt * 512 + c * 32 + 2 * dp];
    biasH[gt][1] = bhh_l[gt * 512 + c * 32 + 2 * dp + 1];
    biasI[gt][0] = l2 ? bih2[gt * 512 + c * 32 + 2 * dp] : 0.0f;
    biasI[gt][1] = l2 ? bih2[gt * 512 + c * 32 + 2 * dp + 1] : 0.0f;
  }

  u32* const ringOwn = l2 ? h2ring : h1ring;
  const int my = ga * 256 + c * 16 + dp;   // this thread's u32 slot within a ring slot
  u32 hpp_reg = 0;                         // carried hprev (own prior publish)

  for (int t = t0; t < t1; ++t) {
    // L1: prefetch xp for this step (drained by the poll's vmcnt(0))
    u32 xu[3];
    if (!l2) {
      const size_t row = ((size_t)(ga << lgT) + (size_t)(t - t0)) * 768;
#pragma unroll
      for (int gt = 0; gt < 3; ++gt)
        xu[gt] = xp[row + gt * 256 + c * 16 + dp];
    }

    // poison-poll: per-wave, the data loads ARE the detection
    const u32* rdA = ringOwn + (size_t)(t & 15) * 8192 + (tid << 2);
    const u32* rdB = h1ring + (size_t)((t + 1) & 15) * 8192 + (tid << 2);
    u32x4v a0, a1, a2, a3, b0, b1, b2, b3;
    while (true) {
      a0 = llc_load128_async(rdA);
      a1 = llc_load128_async(rdA + 2048);
      a2 = llc_load128_async(rdA + 4096);
      a3 = llc_load128_async(rdA + 6144);
      if (l2) {
        b0 = llc_load128_async(rdB);
        b1 = llc_load128_async(rdB + 2048);
        b2 = llc_load128_async(rdB + 4096);
        b3 = llc_load128_async(rdB + 6144);
      }
      u32 prog = 0;
      if (!l2) prog = llc_load32(&syncw[0]);
      asm volatile("s_waitcnt vmcnt(0)" ::: "memory");
      __builtin_amdgcn_sched_barrier(0);
      int bad = chk4(a0) | chk4(a1) | chk4(a2) | chk4(a3);
      if (l2) bad |= chk4(b0) | chk4(b1) | chk4(b2) | chk4(b3);
      else    bad |= (int)((int)prog < t - 3);
      if (!__any(bad)) break;
      __builtin_amdgcn_s_sleep(1);
    }
    // wave writes its own units to LDS (no pre-barrier needed: per-wave poll)
    {
      const int r0 = tid >> 6;              // row within 8-row chunk
      const int cc = (tid << 2) & 255;      // u32 col
      *(u32x4v*)&st_l[(0  + r0) * 260 + cc] = a0;
      *(u32x4v*)&st_l[(8  + r0) * 260 + cc] = a1;
      *(u32x4v*)&st_l[(16 + r0) * 260 + cc] = a2;
      *(u32x4v*)&st_l[(24 + r0) * 260 + cc] = a3;
      if (l2) {
        *(u32x4v*)&h1_l[(0  + r0) * 260 + cc] = b0;
        *(u32x4v*)&h1_l[(8  + r0) * 260 + cc] = b1;
        *(u32x4v*)&h1_l[(16 + r0) * 260 + cc] = b2;
        *(u32x4v*)&h1_l[(24 + r0) * 260 + cc] = b3;
      }
    }
    __syncthreads();   // B1

    // re-poison own region of slot used at step t+8 early — ack overlaps MFMA.
    // Safety: slot (t+9)&15 holds version t-7 data; every reader of it is >=3 steps done.
    llc_store32(&ringOwn[(size_t)((t + 9) & 15) * 8192 + c * 512 + tid], POIS);

    // hprev from own prior publish (LDS only on first iteration)
    const u32 hpp = (t == t0) ? st_l[ga * 260 + c * 16 + dp] : hpp_reg;

    if (mfma_w) {
      // ILP-2: two independent 16-deep chains, summed at the end
      f32x16 accA, accB;
#pragma unroll
      for (int i = 0; i < 16; ++i) { accA[i] = 0.0f; accB[i] = 0.0f; }
      const u32* asrc = (w < 3) ? st_l : h1_l;
#pragma unroll
      for (int ks = 0; ks < 16; ++ks) {
        const half8 afA = *(const half8*)&asrc[l31 * 260 + ks * 8 + kh * 4];
        const half8 afB = *(const half8*)&asrc[l31 * 260 + (ks + 16) * 8 + kh * 4];
        accA = __builtin_amdgcn_mfma_f32_32x32x16_f16(afA, bf[ks], accA, 0, 0, 0);
        accB = __builtin_amdgcn_mfma_f32_32x32x16_f16(afB, bf[ks + 16], accB, 0, 0, 0);
      }
      // C/D map (verified): col=l31 -> local row, row=(r&3)+8*(r>>2)+4*kh -> group
      const int gt = (w < 3) ? w : w - 3;
      float* sg = (w < 3) ? sg_h : sg_i;
#pragma unroll
      for (int r = 0; r < 16; ++r) {
        const int grp = (r & 3) + 8 * (r >> 2) + 4 * kh;
        sg[(gt * 32 + l31) * 33 + grp] = accA[r] + accB[r];
      }
    }
    __syncthreads();   // B2

    // epilogue: one group x one dim-pair per thread
    float hn0, hn1;
    {
      const half2t hp2 = __builtin_bit_cast(half2t, hpp);
      float hn[2];
#pragma unroll
      for (int dd = 0; dd < 2; ++dd) {
        const int d = 2 * dp + dd;
        float xr, xz, xn;
        if (!l2) {
          const half2t xr2 = __builtin_bit_cast(half2t, xu[0]);
          const half2t xz2 = __builtin_bit_cast(half2t, xu[1]);
          const half2t xn2 = __builtin_bit_cast(half2t, xu[2]);
          xr = (float)(dd ? xr2.y : xr2.x);
          xz = (float)(dd ? xz2.y : xz2.x);
          xn = (float)(dd ? xn2.y : xn2.x);
        } else {
          xr = sg_i[(0 * 32 + d) * 33 + ga] + biasI[0][dd];
          xz = sg_i[(32 + d) * 33 + ga]     + biasI[1][dd];
          xn = sg_i[(64 + d) * 33 + ga]     + biasI[2][dd];
        }
        const float hprev = (float)(dd ? hp2.y : hp2.x);
        const float rr = fast_sigmoid(xr + sg_h[(0 * 32 + d) * 33 + ga] + biasH[0][dd]);
        const float zz = fast_sigmoid(xz + sg_h[(32 + d) * 33 + ga]     + biasH[1][dd]);
        const float nn = fast_tanh(xn + rr * (sg_h[(64 + d) * 33 + ga]  + biasH[2][dd]));
        hn[dd] = (1.0f - zz) * nn + zz * hprev;
      }
      hn0 = hn[0]; hn1 = hn[1];
    }
    const u32 packed = pack2h(hn0, hn1);
    hpp_reg = packed;
    // publish h_{t+1} (no drain, no flag — consumers detect via poison clearing)
    llc_store32(&ringOwn[(size_t)((t + 1) & 15) * 8192 + my], packed);
    // deferred fp32 output store (off the sync path)
    if (l2) {
      float2 v; v.x = hn0; v.y = hn1;
      *(float2*)&out[((size_t)ga * TLEN + t) * HDIM + c * 32 + 2 * dp] = v;
    }
    // L2 progress (one block publishes; intra-layer skew <= 1)
    if (l2 && c == 0 && tid == 0) llc_store32(&syncw[0], (u32)(t + 1));
  }
}

// ---------------- host launcher ----------------
extern "C" void kernel_launch(void* const* d_in, const int* in_sizes, int n_in,
                              void* d_out, int out_size, void* d_ws, size_t ws_size,
                              hipStream_t stream)
{
  const float* x     = (const float*)d_in[0];
  const float* gamma = (const float*)d_in[1];
  const float* beta  = (const float*)d_in[2];
  const float* Wih   = (const float*)d_in[3];
  const float* Whh   = (const float*)d_in[4];
  const float* bih   = (const float*)d_in[5];
  const float* bhh   = (const float*)d_in[6];
  float* out = (float*)d_out;

  // ws layout: [xp][hseq 67MB][wih_h][whh_h][h1ring][h2ring][syncw]
  const size_t wbytes  = (size_t)2 * G3 * HDIM * 2;                 // 3,145,728 each
  const size_t hseqb   = (size_t)BATCH * TLEN * HDIM * 2;           // 67,108,864
  const size_t ringb   = (size_t)NSLOT * 8192 * 4;                  // 524,288 each
  const size_t fixed   = hseqb + 2 * wbytes + 2 * ringb + 4096;
  int lgT = 11;
  while (lgT > 2 && ((size_t)BATCH * ((size_t)1 << lgT) * G3 * 2 + fixed) > ws_size) --lgT;
  const int TSEG = 1 << lgT;
  const int nseg = TLEN / TSEG;

  char* ws = (char*)d_ws;
  _Float16* xp     = (_Float16*)ws;
  char* base       = ws + (size_t)BATCH * TSEG * G3 * 2;
  _Float16* hseq   = (_Float16*)base;                               // LN output (fp16)
  _Float16* wih_h  = (_Float16*)(base + hseqb);
  _Float16* whh_h  = (_Float16*)(base + hseqb + wbytes);
  u32*      h1ring = (u32*)    (base + hseqb + 2 * wbytes);
  u32*      h2ring = h1ring + (size_t)NSLOT * 8192;
  u32*      syncw  = h2ring + (size_t)NSLOT * 8192;

  convert_weights<<<512, 256, 0, stream>>>(Wih, Whh, wih_h, whh_h);
  ln_kernel<<<BATCH * TLEN, 256, 0, stream>>>(x, gamma, beta, hseq);
  init_sync<<<512, 256, 0, stream>>>(h1ring, h2ring, syncw);

  const dim3 ggrid(BATCH * TSEG / 128, 12);
  for (int s = 0; s < nseg; ++s) {
    const int t0 = s * TSEG;
    gemm_f16<<<ggrid, 256, 0, stream>>>(hseq, wih_h, bih, xp, t0, lgT);
    gru_fused<<<32, 512, 0, stream>>>((const u32*)xp, (const u32*)whh_h,
                                      (const u32*)(wih_h + (size_t)G3 * HDIM),
                                      bhh, bih + G3, out,
                                      h1ring, h2ring, syncw, t0, t0 + TSEG, lgT);
  }
}